// Round 1
// baseline (259.960 us; speedup 1.0000x reference)
//
#include <hip/hip_runtime.h>

// MPCM: multi-scale patch contrast measure + per-image mean+3*std threshold.
// All interior math in double so the binary (out > th) decision matches a
// float64 numpy reference to ~1e-15 (binary output => flips are fatal).

namespace {

constexpr int H = 512, W = 512, NIMG = 16;
constexpr int T = 32;                    // output tile
constexpr int HALO = 13;                 // max k + k/2 = 9 + 4
constexpr int IN_DIM = T + 2 * HALO;     // 58
constexpr int TILES = H / T;             // 16
constexpr int NTHREADS = 256;
constexpr int PPT = (T * T) / NTHREADS;  // 4 pixels per thread

struct Smem {
  float  in[IN_DIM * IN_DIM];  // 13456 B
  double rs[58 * 50];          // 23200 B (row sums, max RKxLK)
  double L [50 * 50];          // 20000 B (box means, max LKxLK)
};                             // total 56656 B < 64 KB

// One scale: separable box sum -> box mean (zeroed outside image) -> pcm -> max into mp[].
template <int K>
__device__ __forceinline__ void scale_pass(Smem& s, int y0, int x0, double mp[PPT]) {
  constexpr int R    = K / 2;
  constexpr int LK   = T + 2 * K;       // box-mean region side
  constexpr int RK   = T + 3 * K - 1;   // row-sum rows needed
  constexpr int ROFF = HALO - K - R;    // rs row -> input row offset
  constexpr int COFF = HALO - K;        // L col -> input col offset
  const int tid = threadIdx.x;

  // row sums of input (zero-padded via halo load)
  for (int e = tid; e < RK * LK; e += NTHREADS) {
    const int row = e / LK, col = e % LK;
    double a = 0.0;
#pragma unroll
    for (int j = 0; j < K; ++j)
      a += (double)s.in[(row + ROFF) * IN_DIM + (col + COFF - R + j)];
    s.rs[row * LK + col] = a;
  }
  __syncthreads();

  // column sums -> box mean; force 0 outside the image (shifted-neighbor semantics)
  constexpr double inv = 1.0 / (double)(K * K);
  for (int e = tid; e < LK * LK; e += NTHREADS) {
    const int yy = e / LK, xx = e % LK;
    double a = 0.0;
#pragma unroll
    for (int j = 0; j < K; ++j) a += s.rs[(yy + j) * LK + xx];
    const int gy = y0 - K + yy, gx = x0 - K + xx;
    const bool inside = (gy >= 0) & (gy < H) & (gx >= 0) & (gx < W);
    s.L[e] = inside ? a * inv : 0.0;
  }
  __syncthreads();

  // pcm: diffs to 8 dilated neighbors, paired products [0,4][1,5][2,6][3,7], min, running max
#pragma unroll
  for (int i = 0; i < PPT; ++i) {
    const int lin = tid + i * NTHREADS;
    const int ty = lin >> 5, tx = lin & 31;
    const int cy = ty + K, cx = tx + K;
    const double c  = s.L[cy * LK + cx];
    const double d0 = c - s.L[(cy - K) * LK + (cx - K)];  // (-1,-1)
    const double d1 = c - s.L[(cy - K) * LK + cx];        // (-1, 0)
    const double d2 = c - s.L[(cy - K) * LK + (cx + K)];  // (-1, 1)
    const double d3 = c - s.L[cy * LK + (cx - K)];        // ( 0,-1)
    const double d4 = c - s.L[cy * LK + (cx + K)];        // ( 0, 1)
    const double d5 = c - s.L[(cy + K) * LK + (cx - K)];  // ( 1,-1)
    const double d6 = c - s.L[(cy + K) * LK + cx];        // ( 1, 0)
    const double d7 = c - s.L[(cy + K) * LK + (cx + K)];  // ( 1, 1)
    const double p0 = d0 * d4, p1 = d1 * d5, p2 = d2 * d6, p3 = d3 * d7;
    const double m = fmin(fmin(p0, p1), fmin(p2, p3));
    mp[i] = fmax(mp[i], m);
  }
  __syncthreads();
}

__device__ __forceinline__ void compute_tile(Smem& s, const float* img, int y0, int x0,
                                             double mp[PPT]) {
  const int tid = threadIdx.x;
  for (int e = tid; e < IN_DIM * IN_DIM; e += NTHREADS) {
    const int iy = e / IN_DIM, ix = e % IN_DIM;
    const int gy = y0 - HALO + iy, gx = x0 - HALO + ix;
    float v = 0.0f;
    if (gy >= 0 && gy < H && gx >= 0 && gx < W) v = img[gy * W + gx];
    s.in[e] = v;
  }
#pragma unroll
  for (int i = 0; i < PPT; ++i) mp[i] = -1.0e300;
  __syncthreads();
  scale_pass<3>(s, y0, x0, mp);
  scale_pass<5>(s, y0, x0, mp);
  scale_pass<7>(s, y0, x0, mp);
  scale_pass<9>(s, y0, x0, mp);
}

// Pass 1: per-block (sum, sumsq) of mpcm, fixed-order tree reduction -> partials
__global__ __launch_bounds__(NTHREADS) void k_stats(const float* __restrict__ in,
                                                    double* __restrict__ partials) {
  __shared__ Smem s;
  const int img = blockIdx.z, tyb = blockIdx.y, txb = blockIdx.x;
  double mp[PPT];
  compute_tile(s, in + (size_t)img * H * W, tyb * T, txb * T, mp);

  double s1 = 0.0, s2 = 0.0;
#pragma unroll
  for (int i = 0; i < PPT; ++i) { s1 += mp[i]; s2 += mp[i] * mp[i]; }

  double* red = s.rs;  // reuse (disjoint from L which pcm read; barrier below)
  red[threadIdx.x] = s1;
  red[NTHREADS + threadIdx.x] = s2;
  __syncthreads();
  for (int st = NTHREADS / 2; st > 0; st >>= 1) {
    if (threadIdx.x < st) {
      red[threadIdx.x] += red[threadIdx.x + st];
      red[NTHREADS + threadIdx.x] += red[NTHREADS + threadIdx.x + st];
    }
    __syncthreads();
  }
  if (threadIdx.x == 0) {
    const int bl = (img * TILES + tyb) * TILES + txb;
    partials[2 * bl]     = red[0];
    partials[2 * bl + 1] = red[NTHREADS];
  }
}

// Pass 2: per-image sequential (deterministic) reduction -> th = mean + 3*std(ddof=1)
__global__ void k_thresh(const double* __restrict__ partials, double* __restrict__ th) {
  const int img = threadIdx.x;
  if (img < NIMG) {
    double S = 0.0, S2 = 0.0;
    const int nb = TILES * TILES;
    for (int b = 0; b < nb; ++b) {
      const int bl = img * nb + b;
      S  += partials[2 * bl];
      S2 += partials[2 * bl + 1];
    }
    const double N = (double)(H * W);
    const double mean = S / N;
    double var = (S2 - S * S / N) / (N - 1.0);
    if (var < 0.0) var = 0.0;
    th[img] = mean + 3.0 * sqrt(var);
  }
}

// Pass 3: recompute identical mpcm (bit-identical double path), write binary output
__global__ __launch_bounds__(NTHREADS) void k_out(const float* __restrict__ in,
                                                  const double* __restrict__ th,
                                                  float* __restrict__ out) {
  __shared__ Smem s;
  const int img = blockIdx.z, tyb = blockIdx.y, txb = blockIdx.x;
  double mp[PPT];
  compute_tile(s, in + (size_t)img * H * W, tyb * T, txb * T, mp);
  const double t = th[img];
#pragma unroll
  for (int i = 0; i < PPT; ++i) {
    const int lin = threadIdx.x + i * NTHREADS;
    const int ty = lin >> 5, tx = lin & 31;
    const int gy = tyb * T + ty, gx = txb * T + tx;
    out[(size_t)img * H * W + gy * W + gx] = (mp[i] > t) ? 1.0f : 0.0f;
  }
}

}  // namespace

extern "C" void kernel_launch(void* const* d_in, const int* in_sizes, int n_in,
                              void* d_out, int out_size, void* d_ws, size_t ws_size,
                              hipStream_t stream) {
  const float* in = (const float*)d_in[0];
  float* out = (float*)d_out;

  // ws layout: [0,128)  th (16 doubles)
  //            [256, 256 + 4096*16) partials (4096 blocks x {sum,sumsq})
  double* th = (double*)d_ws;
  double* partials = (double*)((char*)d_ws + 256);

  dim3 grid(TILES, TILES, NIMG);
  k_stats<<<grid, NTHREADS, 0, stream>>>(in, partials);
  k_thresh<<<1, 64, 0, stream>>>(partials, th);
  k_out<<<grid, NTHREADS, 0, stream>>>(in, th, out);
}

// Round 2
// 116.545 us; speedup vs baseline: 2.2306x; 2.2306x over previous
//
#include <hip/hip_runtime.h>

// MPCM: multi-scale patch contrast measure + per-image mean+3*std threshold.
// f64 interior math (binary output => threshold flips are fatal).
// v2: per-tile integral image (box sum = 4 reads, any K), mpcm cached in ws,
//     LDS shrunk via unions (3 blocks/CU), conflict-free strides.

namespace {

constexpr int H = 512, W = 512, NIMG = 16;
constexpr int T = 32;                    // output tile
constexpr int HALO = 13;                 // max k + k/2 = 9 + 4
constexpr int IN = T + 2 * HALO;         // 58
constexpr int TILES = H / T;             // 16
constexpr int NT = 256;
constexpr int PPT = (T * T) / NT;        // 4 pixels per thread
constexpr int WI = 61;                   // I row stride (doubles, odd -> low conflicts)
constexpr int LSTR = 52;                 // L row stride (doubles)

struct Smem {
  double I[59 * WI];                     // 28792 B  exclusive 2D prefix (59 rows used)
  union {
    float  inf[IN * 61];                 // 14152 B  staged input (stride 61)
    double L[50 * LSTR];                 // 20800 B  box means for current scale
    double red[2 * NT];                  //  4096 B  stats reduction
  } u;
};                                       // total 49592 B -> 3 blocks/CU

// One scale: box means from integral (zeroed outside image) -> pcm -> max into mp[].
template <int K>
__device__ __forceinline__ void scale_pass(Smem& s, int y0, int x0, double mp[PPT]) {
  constexpr int R  = K / 2;
  constexpr int LK = T + 2 * K;          // box-mean region side
  const int tid = threadIdx.x;
  constexpr double inv = 1.0 / (double)(K * K);

  for (int e = tid; e < LK * LK; e += NT) {
    const int yy = e / LK, xx = e - yy * LK;
    const int iy = yy + (HALO - K), ix = xx + (HALO - K);   // local center coords
    const double* Ia = s.I + (iy - R) * WI;                 // window top row
    const double* Ib = s.I + (iy + R + 1) * WI;             // window bottom+1 row
    const double sum = Ib[ix + R + 1] - Ia[ix + R + 1] - Ib[ix - R] + Ia[ix - R];
    const int gy = y0 - K + yy, gx = x0 - K + xx;
    const bool inside = ((unsigned)gy < (unsigned)H) & ((unsigned)gx < (unsigned)W);
    s.u.L[yy * LSTR + xx] = inside ? sum * inv : 0.0;
  }
  __syncthreads();

  // pcm: diffs to 8 dilated neighbors, pair products [0,4][1,5][2,6][3,7], min, running max
#pragma unroll
  for (int i = 0; i < PPT; ++i) {
    const int lin = tid + i * NT;
    const int ty = lin >> 5, tx = lin & 31;
    const double* Lc = &s.u.L[(ty + K) * LSTR + (tx + K)];
    const double c  = Lc[0];
    const double d0 = c - Lc[-K * LSTR - K];
    const double d1 = c - Lc[-K * LSTR];
    const double d2 = c - Lc[-K * LSTR + K];
    const double d3 = c - Lc[-K];
    const double d4 = c - Lc[K];
    const double d5 = c - Lc[K * LSTR - K];
    const double d6 = c - Lc[K * LSTR];
    const double d7 = c - Lc[K * LSTR + K];
    const double m = fmin(fmin(d0 * d4, d1 * d5), fmin(d2 * d6, d3 * d7));
    mp[i] = fmax(mp[i], m);
  }
  __syncthreads();
}

__device__ __forceinline__ void compute_tile(Smem& s, const float* img, int y0, int x0,
                                             double mp[PPT]) {
  const int tid = threadIdx.x;
  // stage input (zero padded), stride 61
  for (int e = tid; e < IN * IN; e += NT) {
    const int iy = e / IN, ix = e - iy * IN;
    const int gy = y0 - HALO + iy, gx = x0 - HALO + ix;
    float v = 0.0f;
    if ((unsigned)gy < (unsigned)H && (unsigned)gx < (unsigned)W) v = img[gy * W + gx];
    s.u.inf[iy * 61 + ix] = v;
  }
  // zero row 0 and col 0 of I
  for (int e = tid; e < WI; e += NT) s.I[e] = 0.0;
  for (int e = tid; e < 59; e += NT) s.I[e * WI] = 0.0;
  __syncthreads();

  // row prefix: thread y handles row y (serial over x; running sum in register)
  if (tid < IN) {
    const float* src = &s.u.inf[tid * 61];
    double* dst = &s.I[(tid + 1) * WI + 1];
    double run = 0.0;
#pragma unroll 2
    for (int x = 0; x < IN; ++x) { run += (double)src[x]; dst[x] = run; }
  }
  __syncthreads();

  // col prefix in-place: thread x handles column x+1 (reads row-contiguous across lanes)
  if (tid < IN) {
    double* p = &s.I[WI + (tid + 1)];
    double run = 0.0;
#pragma unroll 2
    for (int y = 0; y < IN; ++y) { run += *p; *p = run; p += WI; }
  }
  __syncthreads();

#pragma unroll
  for (int i = 0; i < PPT; ++i) mp[i] = -1.0e300;
  scale_pass<3>(s, y0, x0, mp);
  scale_pass<5>(s, y0, x0, mp);
  scale_pass<7>(s, y0, x0, mp);
  scale_pass<9>(s, y0, x0, mp);
}

// Pass 1: mpcm -> (optional) ws cache + per-block (sum, sumsq), fixed-order reduction
__global__ __launch_bounds__(NT, 3) void k_stats(const float* __restrict__ in,
                                                 double* __restrict__ partials,
                                                 double* __restrict__ wsmp) {
  __shared__ Smem s;
  const int img = blockIdx.z, tyb = blockIdx.y, txb = blockIdx.x;
  double mp[PPT];
  compute_tile(s, in + (size_t)img * H * W, tyb * T, txb * T, mp);

  if (wsmp != nullptr) {
#pragma unroll
    for (int i = 0; i < PPT; ++i) {
      const int lin = threadIdx.x + i * NT;
      const int ty = lin >> 5, tx = lin & 31;
      const int gy = tyb * T + ty, gx = txb * T + tx;
      wsmp[(size_t)img * H * W + gy * W + gx] = mp[i];
    }
  }

  double s1 = 0.0, s2 = 0.0;
#pragma unroll
  for (int i = 0; i < PPT; ++i) { s1 += mp[i]; s2 += mp[i] * mp[i]; }

  double* red = s.u.red;  // last scale_pass ended with a barrier; L is dead
  red[threadIdx.x] = s1;
  red[NT + threadIdx.x] = s2;
  __syncthreads();
  for (int st = NT / 2; st > 0; st >>= 1) {
    if (threadIdx.x < st) {
      red[threadIdx.x] += red[threadIdx.x + st];
      red[NT + threadIdx.x] += red[NT + threadIdx.x + st];
    }
    __syncthreads();
  }
  if (threadIdx.x == 0) {
    const int bl = (img * TILES + tyb) * TILES + txb;
    partials[2 * bl]     = red[0];
    partials[2 * bl + 1] = red[NT];
  }
}

// Pass 2: per-image sequential (deterministic) reduction -> th = mean + 3*std(ddof=1)
__global__ void k_thresh(const double* __restrict__ partials, double* __restrict__ th) {
  const int img = threadIdx.x;
  if (img < NIMG) {
    double S = 0.0, S2 = 0.0;
    const int nb = TILES * TILES;
    for (int b = 0; b < nb; ++b) {
      S  += partials[2 * (img * nb + b)];
      S2 += partials[2 * (img * nb + b) + 1];
    }
    const double N = (double)(H * W);
    const double mean = S / N;
    double var = (S2 - S * S / N) / (N - 1.0);
    if (var < 0.0) var = 0.0;
    th[img] = mean + 3.0 * sqrt(var);
  }
}

// Pass 3a (fast): compare cached mpcm against threshold (memory-bound)
__global__ __launch_bounds__(NT) void k_out_cached(const double* __restrict__ wsmp,
                                                   const double* __restrict__ th,
                                                   float* __restrict__ out) {
  const int n = NIMG * H * W;
  for (int idx = blockIdx.x * NT + threadIdx.x; idx < n; idx += gridDim.x * NT) {
    const double t = th[idx >> 18];  // H*W = 2^18
    out[idx] = (wsmp[idx] > t) ? 1.0f : 0.0f;
  }
}

// Pass 3b (fallback): recompute identical mpcm, write binary output
__global__ __launch_bounds__(NT, 3) void k_out_full(const float* __restrict__ in,
                                                    const double* __restrict__ th,
                                                    float* __restrict__ out) {
  __shared__ Smem s;
  const int img = blockIdx.z, tyb = blockIdx.y, txb = blockIdx.x;
  double mp[PPT];
  compute_tile(s, in + (size_t)img * H * W, tyb * T, txb * T, mp);
  const double t = th[img];
#pragma unroll
  for (int i = 0; i < PPT; ++i) {
    const int lin = threadIdx.x + i * NT;
    const int ty = lin >> 5, tx = lin & 31;
    const int gy = tyb * T + ty, gx = txb * T + tx;
    out[(size_t)img * H * W + gy * W + gx] = (mp[i] > t) ? 1.0f : 0.0f;
  }
}

}  // namespace

extern "C" void kernel_launch(void* const* d_in, const int* in_sizes, int n_in,
                              void* d_out, int out_size, void* d_ws, size_t ws_size,
                              hipStream_t stream) {
  const float* in = (const float*)d_in[0];
  float* out = (float*)d_out;

  // ws layout: [0,128)                th (16 doubles)
  //            [4096, 4096+65536)     partials (4096 blocks x {sum,sumsq})
  //            [131072, +33554432)    mpcm cache (optional)
  double* th = (double*)d_ws;
  double* partials = (double*)((char*)d_ws + 4096);
  double* wsmp = (double*)((char*)d_ws + 131072);
  const bool cache = ws_size >= (size_t)131072 + (size_t)NIMG * H * W * 8;

  dim3 grid(TILES, TILES, NIMG);
  k_stats<<<grid, NT, 0, stream>>>(in, partials, cache ? wsmp : nullptr);
  k_thresh<<<1, 64, 0, stream>>>(partials, th);
  if (cache) {
    k_out_cached<<<2048, NT, 0, stream>>>(wsmp, th, out);
  } else {
    k_out_full<<<grid, NT, 0, stream>>>(in, th, out);
  }
}

// Round 3
// 110.782 us; speedup vs baseline: 2.3466x; 1.0520x over previous
//
#include <hip/hip_runtime.h>

// MPCM: multi-scale patch contrast measure + per-image mean+3*std threshold.
// f64 interior math (binary output => threshold flips are fatal).
// v3: 2-consecutive-x pixels per thread -> paired LDS accesses (ds_read2_b64 /
//     ds_write_b128), halving LDS instruction count (the measured bottleneck).

namespace {

constexpr int H = 512, W = 512, NIMG = 16;
constexpr int T = 32;                    // output tile
constexpr int HALO = 13;                 // max k + k/2 = 9 + 4
constexpr int IN = T + 2 * HALO;         // 58
constexpr int TILES = H / T;             // 16
constexpr int NT = 256;
constexpr int WI = 61;                   // I row stride (doubles)
constexpr int LSTR = 52;                 // L row stride (doubles, even -> b128 writes)

struct Smem {
  double I[59 * WI];                     // 28792 B  exclusive 2D prefix
  union alignas(16) {
    float  inf[IN * 61];                 // 14152 B  staged input
    double L[50 * LSTR];                 // 20800 B  box means for current scale
    double red[8];                       //          stats reduction
  } u;
};                                       // ~49.6 KB -> 3 blocks/CU

// One scale: box means from integral (zeroed outside image) -> pcm -> max into mp[4].
// Thread pixel mapping (pcm): pair j in {0,1}: row r=(tid>>4)+16j, cols cc..cc+1, cc=2*(tid&15).
template <int K>
__device__ __forceinline__ void scale_pass(Smem& s, int y0, int x0, double mp[4]) {
  constexpr int R  = K / 2;
  constexpr int LK = T + 2 * K;          // box-mean region side (even)
  constexpr int HP = LK / 2;             // pairs per row
  constexpr int NP = LK * HP;            // total pairs
  constexpr double inv = 1.0 / (double)(K * K);
  const int tid = threadIdx.x;

  for (int pe = tid; pe < NP; pe += NT) {
    const int yy = pe / HP;
    const int xx = (pe - yy * HP) * 2;
    const int iy  = yy + (HALO - K);
    const int ixm = xx + (HALO - K) - R;                    // left corner col
    const double* Ia = s.I + (iy - R) * WI + ixm;           // top row
    const double* Ib = s.I + (iy + R + 1) * WI + ixm;       // bottom+1 row
    const double a0 = Ia[0], a1 = Ia[1], aK = Ia[K], aK1 = Ia[K + 1];
    const double b0 = Ib[0], b1 = Ib[1], bK = Ib[K], bK1 = Ib[K + 1];
    const double s0 = (bK  - aK)  - (b0 - a0);              // ixm+K == ix+R+1
    const double s1 = (bK1 - aK1) - (b1 - a1);
    const int gy = y0 - K + yy, gx = x0 - K + xx;
    const bool in0 = ((unsigned)gy < (unsigned)H) & ((unsigned)gx < (unsigned)W);
    const bool in1 = ((unsigned)gy < (unsigned)H) & ((unsigned)(gx + 1) < (unsigned)W);
    double2 o;
    o.x = in0 ? s0 * inv : 0.0;
    o.y = in1 ? s1 * inv : 0.0;
    *(double2*)&s.u.L[yy * LSTR + xx] = o;                  // 16B aligned (LSTR even, xx even)
  }
  __syncthreads();

#pragma unroll
  for (int j = 0; j < 2; ++j) {
    const int r  = (tid >> 4) + j * 16;
    const int cc = (tid & 15) * 2;
    const double* up  = &s.u.L[r * LSTR + cc];              // row (r+K)-K
    const double* mid = &s.u.L[(r + K) * LSTR + cc];
    const double* dn  = &s.u.L[(r + 2 * K) * LSTR + cc];
    const double u0 = up[0],  u1 = up[1],  uK = up[K],  uK1 = up[K + 1],  u2 = up[2 * K],  u21 = up[2 * K + 1];
    const double m0 = mid[0], m1 = mid[1], mK = mid[K], mK1 = mid[K + 1], m2 = mid[2 * K], m21 = mid[2 * K + 1];
    const double w0 = dn[0],  w1 = dn[1],  wK = dn[K],  wK1 = dn[K + 1],  w2 = dn[2 * K],  w21 = dn[2 * K + 1];
    {
      const double c = mK;
      const double e0 = c - u0, e1 = c - uK, e2 = c - u2, e3 = c - m0;
      const double e4 = c - m2, e5 = c - w0, e6 = c - wK, e7 = c - w2;
      const double m = fmin(fmin(e0 * e4, e1 * e5), fmin(e2 * e6, e3 * e7));
      mp[2 * j] = fmax(mp[2 * j], m);
    }
    {
      const double c = mK1;
      const double e0 = c - u1, e1 = c - uK1, e2 = c - u21, e3 = c - m1;
      const double e4 = c - m21, e5 = c - w1, e6 = c - wK1, e7 = c - w21;
      const double m = fmin(fmin(e0 * e4, e1 * e5), fmin(e2 * e6, e3 * e7));
      mp[2 * j + 1] = fmax(mp[2 * j + 1], m);
    }
  }
  __syncthreads();
}

__device__ __forceinline__ void compute_tile(Smem& s, const float* __restrict__ img,
                                             int y0, int x0, double mp[4]) {
  const int tid = threadIdx.x;
  for (int e = tid; e < IN * IN; e += NT) {
    const int iy = e / IN, ix = e - iy * IN;
    const int gy = y0 - HALO + iy, gx = x0 - HALO + ix;
    float v = 0.0f;
    if ((unsigned)gy < (unsigned)H && (unsigned)gx < (unsigned)W) v = img[gy * W + gx];
    s.u.inf[iy * 61 + ix] = v;
  }
  for (int e = tid; e < WI; e += NT) s.I[e] = 0.0;
  for (int e = tid; e < 59; e += NT) s.I[e * WI] = 0.0;
  __syncthreads();

  // row prefix: thread y handles row y, 2 elements/iter (read2_b32 + write2_b64)
  if (tid < IN) {
    const float* src = &s.u.inf[tid * 61];
    double* dst = &s.I[(tid + 1) * WI + 1];
#pragma unroll
    for (int x = 0; x < IN; x += 2) {
      const float f0 = src[x], f1 = src[x + 1];
      const double r0 = (x ? dst[x - 1] : 0.0);  // kept in reg by unroll
      const double v0 = r0 + (double)f0;
      const double v1 = v0 + (double)f1;
      dst[x] = v0; dst[x + 1] = v1;
    }
  }
  __syncthreads();

  // col prefix in-place: thread x handles column x+1, 2 rows/iter (read2/write2 offsets 0,WI)
  if (tid < IN) {
    double* p = &s.I[WI + (tid + 1)];
    double run = 0.0;
#pragma unroll
    for (int y = 0; y < IN; y += 2) {
      const double v0 = p[0], v1 = p[WI];
      const double r0 = run + v0;
      run = r0 + v1;
      p[0] = r0; p[WI] = run;
      p += 2 * WI;
    }
  }
  __syncthreads();

  mp[0] = mp[1] = mp[2] = mp[3] = -1.0e300;
  scale_pass<3>(s, y0, x0, mp);
  scale_pass<5>(s, y0, x0, mp);
  scale_pass<7>(s, y0, x0, mp);
  scale_pass<9>(s, y0, x0, mp);
}

// Pass 1: mpcm -> ws cache + per-block (sum, sumsq) via wave shuffles (fixed order)
__global__ __launch_bounds__(NT, 3) void k_stats(const float* __restrict__ in,
                                                 double* __restrict__ partials,
                                                 double* __restrict__ wsmp) {
  __shared__ Smem s;
  const int img = blockIdx.z, tyb = blockIdx.y, txb = blockIdx.x;
  const int y0 = tyb * T, x0 = txb * T;
  double mp[4];
  compute_tile(s, in + (size_t)img * H * W, y0, x0, mp);

  const int tid = threadIdx.x;
  if (wsmp != nullptr) {
#pragma unroll
    for (int j = 0; j < 2; ++j) {
      const int r = (tid >> 4) + j * 16, cc = (tid & 15) * 2;
      double2 v; v.x = mp[2 * j]; v.y = mp[2 * j + 1];
      *(double2*)&wsmp[(size_t)img * H * W + (size_t)(y0 + r) * W + (x0 + cc)] = v;
    }
  }

  double s1 = (mp[0] + mp[1]) + (mp[2] + mp[3]);
  double s2 = (mp[0] * mp[0] + mp[1] * mp[1]) + (mp[2] * mp[2] + mp[3] * mp[3]);
#pragma unroll
  for (int off = 32; off; off >>= 1) {
    s1 += __shfl_down(s1, off);
    s2 += __shfl_down(s2, off);
  }
  if ((tid & 63) == 0) { s.u.red[tid >> 6] = s1; s.u.red[4 + (tid >> 6)] = s2; }
  __syncthreads();
  if (tid == 0) {
    const int bl = (img * TILES + tyb) * TILES + txb;
    partials[2 * bl]     = (s.u.red[0] + s.u.red[1]) + (s.u.red[2] + s.u.red[3]);
    partials[2 * bl + 1] = (s.u.red[4] + s.u.red[5]) + (s.u.red[6] + s.u.red[7]);
  }
}

// Pass 2: per-image sequential (deterministic) reduction -> th = mean + 3*std(ddof=1)
__global__ void k_thresh(const double* __restrict__ partials, double* __restrict__ th) {
  const int img = threadIdx.x;
  if (img < NIMG) {
    double S = 0.0, S2 = 0.0;
    const int nb = TILES * TILES;
    for (int b = 0; b < nb; ++b) {
      S  += partials[2 * (img * nb + b)];
      S2 += partials[2 * (img * nb + b) + 1];
    }
    const double N = (double)(H * W);
    const double mean = S / N;
    double var = (S2 - S * S / N) / (N - 1.0);
    if (var < 0.0) var = 0.0;
    th[img] = mean + 3.0 * sqrt(var);
  }
}

// Pass 3a (fast): compare cached mpcm against threshold (memory-bound, vectorized)
__global__ __launch_bounds__(NT) void k_out_cached(const double* __restrict__ wsmp,
                                                   const double* __restrict__ th,
                                                   float* __restrict__ out) {
  const int n = NIMG * H * W / 2;
  for (int i = blockIdx.x * NT + threadIdx.x; i < n; i += gridDim.x * NT) {
    const double t = th[i >> 17];  // 2 px per i; H*W/2 = 2^17
    const double2 v = ((const double2*)wsmp)[i];
    float2 o; o.x = (v.x > t) ? 1.0f : 0.0f; o.y = (v.y > t) ? 1.0f : 0.0f;
    ((float2*)out)[i] = o;
  }
}

// Pass 3b (fallback): recompute identical mpcm, write binary output
__global__ __launch_bounds__(NT, 3) void k_out_full(const float* __restrict__ in,
                                                    const double* __restrict__ th,
                                                    float* __restrict__ out) {
  __shared__ Smem s;
  const int img = blockIdx.z, tyb = blockIdx.y, txb = blockIdx.x;
  const int y0 = tyb * T, x0 = txb * T;
  double mp[4];
  compute_tile(s, in + (size_t)img * H * W, y0, x0, mp);
  const double t = th[img];
  const int tid = threadIdx.x;
#pragma unroll
  for (int j = 0; j < 2; ++j) {
    const int r = (tid >> 4) + j * 16, cc = (tid & 15) * 2;
    float2 o;
    o.x = (mp[2 * j]     > t) ? 1.0f : 0.0f;
    o.y = (mp[2 * j + 1] > t) ? 1.0f : 0.0f;
    *(float2*)&out[(size_t)img * H * W + (size_t)(y0 + r) * W + (x0 + cc)] = o;
  }
}

}  // namespace

extern "C" void kernel_launch(void* const* d_in, const int* in_sizes, int n_in,
                              void* d_out, int out_size, void* d_ws, size_t ws_size,
                              hipStream_t stream) {
  const float* in = (const float*)d_in[0];
  float* out = (float*)d_out;

  // ws layout: [0,128)                th (16 doubles)
  //            [4096, 4096+65536)     partials (4096 blocks x {sum,sumsq})
  //            [131072, +33554432)    mpcm cache (optional)
  double* th = (double*)d_ws;
  double* partials = (double*)((char*)d_ws + 4096);
  double* wsmp = (double*)((char*)d_ws + 131072);
  const bool cache = ws_size >= (size_t)131072 + (size_t)NIMG * H * W * 8;

  dim3 grid(TILES, TILES, NIMG);
  k_stats<<<grid, NT, 0, stream>>>(in, partials, cache ? wsmp : nullptr);
  k_thresh<<<1, 64, 0, stream>>>(partials, th);
  if (cache) {
    k_out_cached<<<2048, NT, 0, stream>>>(wsmp, th, out);
  } else {
    k_out_full<<<grid, NT, 0, stream>>>(in, th, out);
  }
}